// Round 10
// baseline (975.622 us; speedup 1.0000x reference)
//
#include <hip/hip_runtime.h>
#include <hip/hip_bf16.h>

typedef __attribute__((ext_vector_type(8))) __bf16 bf16x8;
typedef __attribute__((ext_vector_type(4))) float f32x4;

#define MFMA(a,b,c) __builtin_amdgcn_mfma_f32_16x16x32_bf16((a),(b),(c),0,0,0)

__device__ __forceinline__ bf16x8 cvt8(float4 a, float4 b){
  bf16x8 r;
  r[0]=(__bf16)a.x; r[1]=(__bf16)a.y; r[2]=(__bf16)a.z; r[3]=(__bf16)a.w;
  r[4]=(__bf16)b.x; r[5]=(__bf16)b.y; r[6]=(__bf16)b.z; r[7]=(__bf16)b.w;
  return r;
}

// zero (16*n4) bytes of scratch
__global__ void zero_k(int4* __restrict__ p, int n4){
  int i = blockIdx.x*256 + threadIdx.x, st = gridDim.x*256;
  for (; i<n4; i+=st) p[i] = make_int4(0,0,0,0);
}

// Wp: B-operand layout, mats {0:sg,1:dg,2:eg,3:su,4:du}; frag=kt*4+nt;
//     lane holds W[kt*32+(l>>4)*8+j][nt*16+(l&15)]   (2560 frags)
// Wq: transposed A-operand layout, mats {0:eg,1:sg,2:dg}; frag=mt*2+kh;
//     lane holds W[kh*32+(l>>4)*8+j][mt*16+(l&15)] = W^T row mt*16+(l&15)  (1536 frags)
__global__ void wcvt(const float* __restrict__ W_sg, const float* __restrict__ W_dg,
                     const float* __restrict__ W_eg, const float* __restrict__ W_su,
                     const float* __restrict__ W_du,
                     bf16x8* __restrict__ Wp, bf16x8* __restrict__ Wq){
  int tid = blockIdx.x*256 + threadIdx.x;
  if (tid >= 2560 + 1536) return;
  int lane = tid & 63, g = lane>>4, c = lane&15;
  if (tid < 2560){
    int frag = (tid>>6)&7, m = tid>>9;
    const float* Ws[5] = {W_sg, W_dg, W_eg, W_su, W_du};
    const float* W = Ws[m];
    int kt = frag>>2, nt = frag&3;
    bf16x8 v;
    #pragma unroll
    for (int j=0;j<8;j++) v[j] = (__bf16)W[(kt*32+g*8+j)*64 + nt*16 + c];
    Wp[tid] = v;
  } else {
    int t2 = tid - 2560;
    int frag = (t2>>6)&7, m = t2>>9;   // m in 0..2
    const float* Ws[3] = {W_eg, W_sg, W_dg};
    const float* W = Ws[m];
    int mt = frag>>1, kh = frag&1;
    bf16x8 v;
    #pragma unroll
    for (int j=0;j<8;j++) v[j] = (__bf16)W[(kh*32+g*8+j)*64 + mt*16 + c];
    Wq[t2] = v;
  }
}

// 2 node transforms: A_src = nf@W_su+b_su, Bh = nf@W_du+b_du
__global__ __launch_bounds__(256) void node_xform(
    const float* __restrict__ nf, const bf16x8* __restrict__ Wp,
    const float* __restrict__ b_su, const float* __restrict__ b_du,
    float* __restrict__ A_src, float* __restrict__ Bh, int ntiles)
{
  int lane = threadIdx.x & 63;
  int gw = blockIdx.x*4 + (threadIdx.x>>6);
  if (gw >= ntiles) return;
  int g = lane>>4, c = lane&15;
  long base = (long)gw*16;
  const float* rp = nf + (base + c)*64 + g*8;
  float4 a0 = *(const float4*)rp,      a1 = *(const float4*)(rp+4);
  float4 a2 = *(const float4*)(rp+32), a3 = *(const float4*)(rp+36);
  bf16x8 A0 = cvt8(a0,a1), A1 = cvt8(a2,a3);
  const float* biases[2] = {b_su,b_du};
  float* outs[2] = {A_src,Bh};
  const int mats[2] = {3,4};
  #pragma unroll
  for (int i=0;i<2;i++){
    #pragma unroll
    for (int nt=0;nt<4;nt++){
      f32x4 acc = {0.f,0.f,0.f,0.f};
      acc = MFMA(A0, Wp[(mats[i]*8+nt)*64+lane],   acc);
      acc = MFMA(A1, Wp[(mats[i]*8+4+nt)*64+lane], acc);
      int col = c + nt*16;
      float bb = biases[i][col];
      #pragma unroll
      for (int e=0;e<4;e++) outs[i][(base+4*g+e)*64 + col] = acc[e] + bb;
    }
  }
}

// ---- CSR build on dst ----
__global__ void hist_k(const int* __restrict__ dst, int* __restrict__ cnt, int E){
  int i = blockIdx.x*256 + threadIdx.x, st = gridDim.x*256;
  for (; i<E; i+=st) atomicAdd(&cnt[dst[i]], 1);
}

__global__ __launch_bounds__(1024) void scan_k(const int* __restrict__ cnt,
                                               int* __restrict__ row, int Nn){
  __shared__ int part[1024];
  int t = threadIdx.x;
  int C = (Nn + 1023) >> 10;
  int lo = t*C;
  int hi = lo + C; if (hi > Nn) hi = Nn;
  int s = 0;
  for (int i=lo; i<hi; i++) s += cnt[i];
  part[t] = s;
  __syncthreads();
  for (int off=1; off<1024; off<<=1){
    int v = part[t];
    int u = (t>=off) ? part[t-off] : 0;
    __syncthreads();
    part[t] = v + u;
    __syncthreads();
  }
  int excl = (t==0) ? 0 : part[t-1];
  for (int i=lo; i<hi; i++){ row[i] = excl; excl += cnt[i]; }
  if (t==1023) row[Nn] = excl;
}

// fill CSR-position records: {edge_id, src}; cnt2 is the cursor (rowp kept clean)
__global__ void fill_k(const int* __restrict__ src, const int* __restrict__ dst,
                       const int* __restrict__ rowp, int* __restrict__ cnt2,
                       int2* __restrict__ pairs, int E){
  int i = blockIdx.x*256 + threadIdx.x, st = gridDim.x*256;
  for (; i<E; i+=st){
    int d = dst[i];
    int pos = rowp[d] + atomicAdd(&cnt2[d], 1);
    pairs[pos] = make_int2(i, src[i]);
  }
}

// ---- phaseA (transposed MFMA): eid-major; lane c owns edge base+c.
// m[edge][f] for f=mt*16+4g+e held per-lane as am[mt][e] -> 4x 8B packed stores.
// A-operand = Wq (LDS), B-operand = per-lane row fragments (same loads as before).
__global__ __launch_bounds__(256) void phaseA(
    const float* __restrict__ ef, const float* __restrict__ nf,
    const int* __restrict__ src, const int* __restrict__ dst,
    const float* __restrict__ b_sg, const float* __restrict__ b_dg,
    const float* __restrict__ b_eg,
    const bf16x8* __restrict__ Wq,
    __bf16* __restrict__ m16, int ntiles)
{
  __shared__ bf16x8 wl[24*64];   // (mat*4+mt)*2+kh; mat 0:eg 1:sg 2:dg
  {
    int t = threadIdx.x;
    #pragma unroll
    for (int i=0;i<6;i++) wl[i*256+t] = Wq[i*256+t];
  }
  __syncthreads();
  int lane = threadIdx.x & 63, g = lane>>4, c = lane&15;
  int gw = blockIdx.x*4 + (threadIdx.x>>6);
  int nw = gridDim.x*4;
  float bias2[4][4];
  #pragma unroll
  for (int mt=0;mt<4;mt++)
    #pragma unroll
    for (int e=0;e<4;e++){
      int f = mt*16 + 4*g + e;
      bias2[mt][e] = b_sg[f] + b_dg[f] + b_eg[f];
    }
  int sc = 0, dc = 0;
  if (gw < ntiles){ sc = src[(long)gw*16 + c]; dc = dst[(long)gw*16 + c]; }
  for (int tt=gw; tt<ntiles; tt+=nw){
    long base = (long)tt*16;
    int tn = tt + nw;
    int sn = sc, dn = dc;
    if (tn < ntiles){ sn = src[(long)tn*16 + c]; dn = dst[(long)tn*16 + c]; }
    const float* rpe = ef + (base+c)*64 + g*8;
    const float* rps = nf + (long)sc*64 + g*8;
    const float* rpd = nf + (long)dc*64 + g*8;
    float4 e0=*(const float4*)rpe,      e1=*(const float4*)(rpe+4);
    float4 e2=*(const float4*)(rpe+32), e3=*(const float4*)(rpe+36);
    float4 s0=*(const float4*)rps,      s1=*(const float4*)(rps+4);
    float4 s2=*(const float4*)(rps+32), s3=*(const float4*)(rps+36);
    float4 d0=*(const float4*)rpd,      d1=*(const float4*)(rpd+4);
    float4 d2=*(const float4*)(rpd+32), d3=*(const float4*)(rpd+36);
    bf16x8 BE0=cvt8(e0,e1), BE1=cvt8(e2,e3);
    bf16x8 BS0=cvt8(s0,s1), BS1=cvt8(s2,s3);
    bf16x8 BD0=cvt8(d0,d1), BD1=cvt8(d2,d3);
    #pragma unroll
    for (int mt=0;mt<4;mt++){
      f32x4 am = {0.f,0.f,0.f,0.f};
      am = MFMA(wl[((0*4+mt)*2+0)*64+lane], BE0, am);
      am = MFMA(wl[((0*4+mt)*2+1)*64+lane], BE1, am);
      am = MFMA(wl[((1*4+mt)*2+0)*64+lane], BS0, am);
      am = MFMA(wl[((1*4+mt)*2+1)*64+lane], BS1, am);
      am = MFMA(wl[((2*4+mt)*2+0)*64+lane], BD0, am);
      am = MFMA(wl[((2*4+mt)*2+1)*64+lane], BD1, am);
      union { __bf16 h[4]; uint2 u; } pk;
      #pragma unroll
      for (int e=0;e<4;e++) pk.h[e] = (__bf16)(am[e] + bias2[mt][e]);
      *(uint2*)(m16 + (base+c)*64 + mt*16 + 4*g) = pk.u;
    }
    sc = sn; dc = dn;
  }
}

// ---- phaseB: node-major over CSR rows. Gather m16[eid] + Bh[src] rows,
// sigma=sigmoid(m), column sums -> h -> x_pre; BOTH BN stat sets.
// 8-edge unroll: 16 independent loads in flight per wave.
__global__ __launch_bounds__(256) void phaseB(
    const __bf16* __restrict__ m16, const int2* __restrict__ pairs,
    const float* __restrict__ Bh, const int* __restrict__ rowp,
    float* __restrict__ A_src,          // in/out -> x_pre
    float* __restrict__ est, float* __restrict__ nst, int Nn)
{
  __shared__ float sst[256];
  sst[threadIdx.x] = 0.f;
  __syncthreads();
  int lane = threadIdx.x & 63, w = threadIdx.x>>6;
  int chunk = (Nn + gridDim.x - 1)/gridDim.x;
  int n0 = blockIdx.x*chunk;
  int n1 = n0 + chunk; if (n1 > Nn) n1 = Nn;
  float e1=0.f, e2=0.f, p1=0.f, p2=0.f;
  for (int n=n0+w; n<n1; n+=4){
    int r0 = rowp[n], r1 = rowp[n+1];
    float ssum=0.f, bsum=0.f;
    int r = r0;
    for (; r+8 <= r1; r+=8){
      int2 q[8];
      #pragma unroll
      for (int j=0;j<8;j++) q[j] = pairs[r+j];
      float mv[8], bh[8];
      #pragma unroll
      for (int j=0;j<8;j++) mv[j] = (float)m16[(long)q[j].x*64 + lane];
      #pragma unroll
      for (int j=0;j<8;j++) bh[j] = Bh[(long)q[j].y*64 + lane];
      #pragma unroll
      for (int j=0;j<8;j++){
        float sg = 1.f/(1.f+__expf(-mv[j]));
        ssum += sg; bsum += bh[j]*sg;
        e1 += mv[j]; e2 += mv[j]*mv[j];
      }
    }
    for (; r < r1; ++r){
      int2 q0 = pairs[r];
      float mv0 = (float)m16[(long)q0.x*64 + lane];
      float bh0 = Bh[(long)q0.y*64 + lane];
      float sg0 = 1.f/(1.f+__expf(-mv0));
      ssum += sg0; bsum += bh0*sg0;
      e1 += mv0;   e2 += mv0*mv0;
    }
    long xi = (long)n*64 + lane;
    float xp = A_src[xi] + bsum/(ssum+1e-6f);
    A_src[xi] = xp;
    p1 += xp; p2 += xp*xp;
  }
  atomicAdd(&sst[lane],     e1);
  atomicAdd(&sst[64+lane],  e2);
  atomicAdd(&sst[128+lane], p1);
  atomicAdd(&sst[192+lane], p2);
  __syncthreads();
  int t = threadIdx.x;
  if (t < 128) atomicAdd(&est[t], sst[t]);
  else         atomicAdd(&nst[t-128], sst[t]);
}

// x = nf + silu(bn(x_pre))
__global__ __launch_bounds__(256) void node_final(
    const float* __restrict__ nf, const float* __restrict__ xpre,
    const float* __restrict__ nst, const float* __restrict__ gam,
    const float* __restrict__ bet, float* __restrict__ xo, int Nn)
{
  long tid = blockIdx.x*blockDim.x + threadIdx.x;
  long stride = (long)gridDim.x*blockDim.x;
  int col = (int)(tid & 63);
  float invN = 1.f/(float)Nn;
  float mu = nst[col]*invN;
  float var = nst[64+col]*invN - mu*mu;
  float rs = rsqrtf(var + 1e-5f);
  float aa = gam[col]*rs;
  float bb = bet[col] - mu*aa;
  long total = (long)Nn*64;
  for (long i=tid; i<total; i+=stride){
    float z = xpre[i]*aa + bb;
    xo[i] = nf[i] + z/(1.f+__expf(-z));
  }
}

// y = ef + silu(bn(m16)) — everything in eid order: pure streaming.
__global__ __launch_bounds__(256) void edge_final(
    const __bf16* __restrict__ m16, const float* __restrict__ ef,
    const float* __restrict__ est, const float* __restrict__ gam,
    const float* __restrict__ bet, float* __restrict__ y, float invE, long E)
{
  int oct = threadIdx.x & 7;
  float aa[8], bb[8];
  #pragma unroll
  for (int j=0;j<8;j++){
    int col = oct*8 + j;
    float mu = est[col]*invE;
    float var = est[64+col]*invE - mu*mu;
    float rs = rsqrtf(var + 1e-5f);
    float ga = gam[col]*rs;
    aa[j] = ga; bb[j] = bet[col] - mu*ga;
  }
  long tid = (long)blockIdx.x*256 + threadIdx.x;
  long pstep = ((long)gridDim.x*256) >> 3;
  for (long p = tid>>3; p < E; p += pstep){
    bf16x8 mv = *(const bf16x8*)&m16[p*64 + oct*8];
    const float* rp = ef + p*64 + oct*8;
    float4 f0 = *(const float4*)rp, f1 = *(const float4*)(rp+4);
    float o[8];
    #pragma unroll
    for (int j=0;j<8;j++){
      float z = aa[j]*(float)mv[j] + bb[j];
      float ev = (j<4) ? ((const float*)&f0)[j] : ((const float*)&f1)[j-4];
      o[j] = ev + z/(1.f+__expf(-z));
    }
    float* yp = y + p*64 + oct*8;
    *(float4*)yp     = make_float4(o[0],o[1],o[2],o[3]);
    *(float4*)(yp+4) = make_float4(o[4],o[5],o[6],o[7]);
  }
}

extern "C" void kernel_launch(void* const* d_in, const int* in_sizes, int n_in,
                              void* d_out, int out_size, void* d_ws, size_t ws_size,
                              hipStream_t stream){
  const float* nf  = (const float*)d_in[0];
  const float* ef  = (const float*)d_in[1];
  const int*   src = (const int*)d_in[2];
  const int*   dst = (const int*)d_in[3];
  const float* W_sg=(const float*)d_in[4];  const float* b_sg=(const float*)d_in[5];
  const float* W_dg=(const float*)d_in[6];  const float* b_dg=(const float*)d_in[7];
  const float* W_eg=(const float*)d_in[8];  const float* b_eg=(const float*)d_in[9];
  const float* W_su=(const float*)d_in[10]; const float* b_su=(const float*)d_in[11];
  const float* W_du=(const float*)d_in[12]; const float* b_du=(const float*)d_in[13];
  const float* gn=(const float*)d_in[14];   const float* btn=(const float*)d_in[15];
  const float* ge=(const float*)d_in[16];   const float* bte=(const float*)d_in[17];

  int Nn = in_sizes[0]/64;
  int Ee = in_sizes[2];
  size_t Nf = (size_t)Nn*64;
  size_t Es = (size_t)Ee;

  float* ws    = (float*)d_ws;
  float* A_src = ws;                          // Nf (becomes x_pre)
  float* Bh    = ws + Nf;                     // Nf
  __bf16* m16  = (__bf16*)(ws + 2*Nf);        // Ee*64 bf16 = 32*Es floats
  int2*  pairs = (int2*)(ws + 2*Nf + 32*Es);  // Es int2 = 2*Es floats
  int*   cnt   = (int*)(pairs + Es);          // Nn
  int*   cnt2  = cnt + Nn;                    // Nn
  float* est   = (float*)(cnt2 + Nn);         // 128
  float* nst   = est + 128;                   // 128
  int*   rowp  = (int*)(nst + 128);           // Nn+1
  size_t woff  = 2*Nf + 32*Es + 2*Es + 2*(size_t)Nn + 256 + (size_t)Nn + 1;
  woff = (woff + 15) & ~(size_t)15;
  bf16x8* Wp   = (bf16x8*)(ws + woff);        // 2560 frags
  bf16x8* Wq   = Wp + 2560;                   // 1536 frags

  float* xo = (float*)d_out;
  float* yo = xo + Nf;

  // zero: cnt, cnt2, est, nst (contiguous, 2*Nn+256 ints)
  int nz4 = (int)((2*(size_t)Nn + 256) >> 2);
  zero_k<<<256,256,0,stream>>>((int4*)cnt, nz4);

  wcvt<<<16,256,0,stream>>>(W_sg,W_dg,W_eg,W_su,W_du,Wp,Wq);

  int ntn = Nn/16;
  node_xform<<<(ntn+3)/4,256,0,stream>>>(nf,Wp,b_su,b_du,A_src,Bh,ntn);
  hist_k<<<2048,256,0,stream>>>(dst,cnt,Ee);
  scan_k<<<1,1024,0,stream>>>(cnt,rowp,Nn);
  fill_k<<<2048,256,0,stream>>>(src,dst,rowp,cnt2,pairs,Ee);
  int nte = Ee/16;
  phaseA<<<4096,256,0,stream>>>(ef,nf,src,dst,b_sg,b_dg,b_eg,Wq,m16,nte);
  phaseB<<<4096,256,0,stream>>>(m16,pairs,Bh,rowp,A_src,est,nst,Nn);
  node_final<<<2048,256,0,stream>>>(nf,A_src,nst,gn,btn,xo,Nn);
  edge_final<<<4096,256,0,stream>>>(m16,ef,est,ge,bte,yo,
                                    1.f/(float)Ee,(long)Ee);
}

// Round 11
// 949.179 us; speedup vs baseline: 1.0279x; 1.0279x over previous
//
#include <hip/hip_runtime.h>
#include <hip/hip_bf16.h>

typedef __attribute__((ext_vector_type(8))) __bf16 bf16x8;
typedef __attribute__((ext_vector_type(4))) float f32x4;

#define MFMA(a,b,c) __builtin_amdgcn_mfma_f32_16x16x32_bf16((a),(b),(c),0,0,0)

__device__ __forceinline__ bf16x8 cvt8(float4 a, float4 b){
  bf16x8 r;
  r[0]=(__bf16)a.x; r[1]=(__bf16)a.y; r[2]=(__bf16)a.z; r[3]=(__bf16)a.w;
  r[4]=(__bf16)b.x; r[5]=(__bf16)b.y; r[6]=(__bf16)b.z; r[7]=(__bf16)b.w;
  return r;
}

// zero (16*n4) bytes of scratch
__global__ void zero_k(int4* __restrict__ p, int n4){
  int i = blockIdx.x*256 + threadIdx.x, st = gridDim.x*256;
  for (; i<n4; i+=st) p[i] = make_int4(0,0,0,0);
}

// Wp: B-operand layout, mats {0:sg,1:dg,2:eg,3:su,4:du}; frag=kt*4+nt;
//     lane holds W[kt*32+(l>>4)*8+j][nt*16+(l&15)]   (2560 frags)
// Wq: transposed A-operand layout, mats {0:eg,1:sg,2:dg}; frag=mt*2+kh;
//     lane holds W[kh*32+(l>>4)*8+j][mt*16+(l&15)] = W^T row mt*16+(l&15)  (1536 frags)
__global__ void wcvt(const float* __restrict__ W_sg, const float* __restrict__ W_dg,
                     const float* __restrict__ W_eg, const float* __restrict__ W_su,
                     const float* __restrict__ W_du,
                     bf16x8* __restrict__ Wp, bf16x8* __restrict__ Wq){
  int tid = blockIdx.x*256 + threadIdx.x;
  if (tid >= 2560 + 1536) return;
  int lane = tid & 63, g = lane>>4, c = lane&15;
  if (tid < 2560){
    int frag = (tid>>6)&7, m = tid>>9;
    const float* Ws[5] = {W_sg, W_dg, W_eg, W_su, W_du};
    const float* W = Ws[m];
    int kt = frag>>2, nt = frag&3;
    bf16x8 v;
    #pragma unroll
    for (int j=0;j<8;j++) v[j] = (__bf16)W[(kt*32+g*8+j)*64 + nt*16 + c];
    Wp[tid] = v;
  } else {
    int t2 = tid - 2560;
    int frag = (t2>>6)&7, m = t2>>9;   // m in 0..2
    const float* Ws[3] = {W_eg, W_sg, W_dg};
    const float* W = Ws[m];
    int mt = frag>>1, kh = frag&1;
    bf16x8 v;
    #pragma unroll
    for (int j=0;j<8;j++) v[j] = (__bf16)W[(kh*32+g*8+j)*64 + mt*16 + c];
    Wq[t2] = v;
  }
}

// 2 node transforms: A_src = nf@W_su+b_su, Bh = nf@W_du+b_du
__global__ __launch_bounds__(256) void node_xform(
    const float* __restrict__ nf, const bf16x8* __restrict__ Wp,
    const float* __restrict__ b_su, const float* __restrict__ b_du,
    float* __restrict__ A_src, float* __restrict__ Bh, int ntiles)
{
  int lane = threadIdx.x & 63;
  int gw = blockIdx.x*4 + (threadIdx.x>>6);
  if (gw >= ntiles) return;
  int g = lane>>4, c = lane&15;
  long base = (long)gw*16;
  const float* rp = nf + (base + c)*64 + g*8;
  float4 a0 = *(const float4*)rp,      a1 = *(const float4*)(rp+4);
  float4 a2 = *(const float4*)(rp+32), a3 = *(const float4*)(rp+36);
  bf16x8 A0 = cvt8(a0,a1), A1 = cvt8(a2,a3);
  const float* biases[2] = {b_su,b_du};
  float* outs[2] = {A_src,Bh};
  const int mats[2] = {3,4};
  #pragma unroll
  for (int i=0;i<2;i++){
    #pragma unroll
    for (int nt=0;nt<4;nt++){
      f32x4 acc = {0.f,0.f,0.f,0.f};
      acc = MFMA(A0, Wp[(mats[i]*8+nt)*64+lane],   acc);
      acc = MFMA(A1, Wp[(mats[i]*8+4+nt)*64+lane], acc);
      int col = c + nt*16;
      float bb = biases[i][col];
      #pragma unroll
      for (int e=0;e<4;e++) outs[i][(base+4*g+e)*64 + col] = acc[e] + bb;
    }
  }
}

// ---- CSR build on dst ----
__global__ void hist_k(const int* __restrict__ dst, int* __restrict__ cnt, int E){
  int i = blockIdx.x*256 + threadIdx.x, st = gridDim.x*256;
  for (; i<E; i+=st) atomicAdd(&cnt[dst[i]], 1);
}

__global__ __launch_bounds__(1024) void scan_k(const int* __restrict__ cnt,
                                               int* __restrict__ row, int Nn){
  __shared__ int part[1024];
  int t = threadIdx.x;
  int C = (Nn + 1023) >> 10;
  int lo = t*C;
  int hi = lo + C; if (hi > Nn) hi = Nn;
  int s = 0;
  for (int i=lo; i<hi; i++) s += cnt[i];
  part[t] = s;
  __syncthreads();
  for (int off=1; off<1024; off<<=1){
    int v = part[t];
    int u = (t>=off) ? part[t-off] : 0;
    __syncthreads();
    part[t] = v + u;
    __syncthreads();
  }
  int excl = (t==0) ? 0 : part[t-1];
  for (int i=lo; i<hi; i++){ row[i] = excl; excl += cnt[i]; }
  if (t==1023) row[Nn] = excl;
}

// fill CSR-position records: {edge_id, src}; cnt2 is the cursor (rowp kept clean)
__global__ void fill_k(const int* __restrict__ src, const int* __restrict__ dst,
                       const int* __restrict__ rowp, int* __restrict__ cnt2,
                       int2* __restrict__ pairs, int E){
  int i = blockIdx.x*256 + threadIdx.x, st = gridDim.x*256;
  for (; i<E; i+=st){
    int d = dst[i];
    int pos = rowp[d] + atomicAdd(&cnt2[d], 1);
    pairs[pos] = make_int2(i, src[i]);
  }
}

// ---- phaseA (transposed MFMA): eid-major; lane c owns edge base+c.
// m[edge][f] for f=mt*16+4g+e held per-lane as am[mt][e] -> 4x 8B packed stores.
// A-operand = Wq (LDS), B-operand = per-lane row fragments (same loads as before).
__global__ __launch_bounds__(256) void phaseA(
    const float* __restrict__ ef, const float* __restrict__ nf,
    const int* __restrict__ src, const int* __restrict__ dst,
    const float* __restrict__ b_sg, const float* __restrict__ b_dg,
    const float* __restrict__ b_eg,
    const bf16x8* __restrict__ Wq,
    __bf16* __restrict__ m16, int ntiles)
{
  __shared__ bf16x8 wl[24*64];   // (mat*4+mt)*2+kh; mat 0:eg 1:sg 2:dg
  {
    int t = threadIdx.x;
    #pragma unroll
    for (int i=0;i<6;i++) wl[i*256+t] = Wq[i*256+t];
  }
  __syncthreads();
  int lane = threadIdx.x & 63, g = lane>>4, c = lane&15;
  int gw = blockIdx.x*4 + (threadIdx.x>>6);
  int nw = gridDim.x*4;
  float bias2[4][4];
  #pragma unroll
  for (int mt=0;mt<4;mt++)
    #pragma unroll
    for (int e=0;e<4;e++){
      int f = mt*16 + 4*g + e;
      bias2[mt][e] = b_sg[f] + b_dg[f] + b_eg[f];
    }
  int sc = 0, dc = 0;
  if (gw < ntiles){ sc = src[(long)gw*16 + c]; dc = dst[(long)gw*16 + c]; }
  for (int tt=gw; tt<ntiles; tt+=nw){
    long base = (long)tt*16;
    int tn = tt + nw;
    int sn = sc, dn = dc;
    if (tn < ntiles){ sn = src[(long)tn*16 + c]; dn = dst[(long)tn*16 + c]; }
    const float* rpe = ef + (base+c)*64 + g*8;
    const float* rps = nf + (long)sc*64 + g*8;
    const float* rpd = nf + (long)dc*64 + g*8;
    float4 e0=*(const float4*)rpe,      e1=*(const float4*)(rpe+4);
    float4 e2=*(const float4*)(rpe+32), e3=*(const float4*)(rpe+36);
    float4 s0=*(const float4*)rps,      s1=*(const float4*)(rps+4);
    float4 s2=*(const float4*)(rps+32), s3=*(const float4*)(rps+36);
    float4 d0=*(const float4*)rpd,      d1=*(const float4*)(rpd+4);
    float4 d2=*(const float4*)(rpd+32), d3=*(const float4*)(rpd+36);
    bf16x8 BE0=cvt8(e0,e1), BE1=cvt8(e2,e3);
    bf16x8 BS0=cvt8(s0,s1), BS1=cvt8(s2,s3);
    bf16x8 BD0=cvt8(d0,d1), BD1=cvt8(d2,d3);
    #pragma unroll
    for (int mt=0;mt<4;mt++){
      f32x4 am = {0.f,0.f,0.f,0.f};
      am = MFMA(wl[((0*4+mt)*2+0)*64+lane], BE0, am);
      am = MFMA(wl[((0*4+mt)*2+1)*64+lane], BE1, am);
      am = MFMA(wl[((1*4+mt)*2+0)*64+lane], BS0, am);
      am = MFMA(wl[((1*4+mt)*2+1)*64+lane], BS1, am);
      am = MFMA(wl[((2*4+mt)*2+0)*64+lane], BD0, am);
      am = MFMA(wl[((2*4+mt)*2+1)*64+lane], BD1, am);
      union { __bf16 h[4]; uint2 u; } pk;
      #pragma unroll
      for (int e=0;e<4;e++) pk.h[e] = (__bf16)(am[e] + bias2[mt][e]);
      *(uint2*)(m16 + (base+c)*64 + mt*16 + 4*g) = pk.u;
    }
    sc = sn; dc = dn;
  }
}

// ---- phaseB: node-major over CSR rows. Gather m16[eid] + Bh[src] rows,
// sigma=sigmoid(m), column sums -> h -> x_pre; BOTH BN stat sets.
// 8-edge unroll: 16 independent loads in flight per wave.
__global__ __launch_bounds__(256) void phaseB(
    const __bf16* __restrict__ m16, const int2* __restrict__ pairs,
    const float* __restrict__ Bh, const int* __restrict__ rowp,
    float* __restrict__ A_src,          // in/out -> x_pre
    float* __restrict__ est, float* __restrict__ nst, int Nn)
{
  __shared__ float sst[256];
  sst[threadIdx.x] = 0.f;
  __syncthreads();
  int lane = threadIdx.x & 63, w = threadIdx.x>>6;
  int chunk = (Nn + gridDim.x - 1)/gridDim.x;
  int n0 = blockIdx.x*chunk;
  int n1 = n0 + chunk; if (n1 > Nn) n1 = Nn;
  float e1=0.f, e2=0.f, p1=0.f, p2=0.f;
  for (int n=n0+w; n<n1; n+=4){
    int r0 = rowp[n], r1 = rowp[n+1];
    float ssum=0.f, bsum=0.f;
    int r = r0;
    for (; r+8 <= r1; r+=8){
      int2 q[8];
      #pragma unroll
      for (int j=0;j<8;j++) q[j] = pairs[r+j];
      float mv[8], bh[8];
      #pragma unroll
      for (int j=0;j<8;j++) mv[j] = (float)m16[(long)q[j].x*64 + lane];
      #pragma unroll
      for (int j=0;j<8;j++) bh[j] = Bh[(long)q[j].y*64 + lane];
      #pragma unroll
      for (int j=0;j<8;j++){
        float sg = 1.f/(1.f+__expf(-mv[j]));
        ssum += sg; bsum += bh[j]*sg;
        e1 += mv[j]; e2 += mv[j]*mv[j];
      }
    }
    for (; r < r1; ++r){
      int2 q0 = pairs[r];
      float mv0 = (float)m16[(long)q0.x*64 + lane];
      float bh0 = Bh[(long)q0.y*64 + lane];
      float sg0 = 1.f/(1.f+__expf(-mv0));
      ssum += sg0; bsum += bh0*sg0;
      e1 += mv0;   e2 += mv0*mv0;
    }
    long xi = (long)n*64 + lane;
    float xp = A_src[xi] + bsum/(ssum+1e-6f);
    A_src[xi] = xp;
    p1 += xp; p2 += xp*xp;
  }
  atomicAdd(&sst[lane],     e1);
  atomicAdd(&sst[64+lane],  e2);
  atomicAdd(&sst[128+lane], p1);
  atomicAdd(&sst[192+lane], p2);
  __syncthreads();
  int t = threadIdx.x;
  if (t < 128) atomicAdd(&est[t], sst[t]);
  else         atomicAdd(&nst[t-128], sst[t]);
}

// x = nf + silu(bn(x_pre))
__global__ __launch_bounds__(256) void node_final(
    const float* __restrict__ nf, const float* __restrict__ xpre,
    const float* __restrict__ nst, const float* __restrict__ gam,
    const float* __restrict__ bet, float* __restrict__ xo, int Nn)
{
  long tid = blockIdx.x*blockDim.x + threadIdx.x;
  long stride = (long)gridDim.x*blockDim.x;
  int col = (int)(tid & 63);
  float invN = 1.f/(float)Nn;
  float mu = nst[col]*invN;
  float var = nst[64+col]*invN - mu*mu;
  float rs = rsqrtf(var + 1e-5f);
  float aa = gam[col]*rs;
  float bb = bet[col] - mu*aa;
  long total = (long)Nn*64;
  for (long i=tid; i<total; i+=stride){
    float z = xpre[i]*aa + bb;
    xo[i] = nf[i] + z/(1.f+__expf(-z));
  }
}

// y = ef + silu(bn(m16)) — everything in eid order: pure streaming.
__global__ __launch_bounds__(256) void edge_final(
    const __bf16* __restrict__ m16, const float* __restrict__ ef,
    const float* __restrict__ est, const float* __restrict__ gam,
    const float* __restrict__ bet, float* __restrict__ y, float invE, long E)
{
  int oct = threadIdx.x & 7;
  float aa[8], bb[8];
  #pragma unroll
  for (int j=0;j<8;j++){
    int col = oct*8 + j;
    float mu = est[col]*invE;
    float var = est[64+col]*invE - mu*mu;
    float rs = rsqrtf(var + 1e-5f);
    float ga = gam[col]*rs;
    aa[j] = ga; bb[j] = bet[col] - mu*ga;
  }
  long tid = (long)blockIdx.x*256 + threadIdx.x;
  long pstep = ((long)gridDim.x*256) >> 3;
  for (long p = tid>>3; p < E; p += pstep){
    bf16x8 mv = *(const bf16x8*)&m16[p*64 + oct*8];
    const float* rp = ef + p*64 + oct*8;
    float4 f0 = *(const float4*)rp, f1 = *(const float4*)(rp+4);
    float o[8];
    #pragma unroll
    for (int j=0;j<8;j++){
      float z = aa[j]*(float)mv[j] + bb[j];
      float ev = (j<4) ? ((const float*)&f0)[j] : ((const float*)&f1)[j-4];
      o[j] = ev + z/(1.f+__expf(-z));
    }
    float* yp = y + p*64 + oct*8;
    *(float4*)yp     = make_float4(o[0],o[1],o[2],o[3]);
    *(float4*)(yp+4) = make_float4(o[4],o[5],o[6],o[7]);
  }
}

extern "C" void kernel_launch(void* const* d_in, const int* in_sizes, int n_in,
                              void* d_out, int out_size, void* d_ws, size_t ws_size,
                              hipStream_t stream){
  const float* nf  = (const float*)d_in[0];
  const float* ef  = (const float*)d_in[1];
  const int*   src = (const int*)d_in[2];
  const int*   dst = (const int*)d_in[3];
  const float* W_sg=(const float*)d_in[4];  const float* b_sg=(const float*)d_in[5];
  const float* W_dg=(const float*)d_in[6];  const float* b_dg=(const float*)d_in[7];
  const float* W_eg=(const float*)d_in[8];  const float* b_eg=(const float*)d_in[9];
  const float* W_su=(const float*)d_in[10]; const float* b_su=(const float*)d_in[11];
  const float* W_du=(const float*)d_in[12]; const float* b_du=(const float*)d_in[13];
  const float* gn=(const float*)d_in[14];   const float* btn=(const float*)d_in[15];
  const float* ge=(const float*)d_in[16];   const float* bte=(const float*)d_in[17];

  int Nn = in_sizes[0]/64;
  int Ee = in_sizes[2];
  size_t Nf = (size_t)Nn*64;
  size_t Es = (size_t)Ee;

  float* ws    = (float*)d_ws;
  float* A_src = ws;                          // Nf (becomes x_pre)
  float* Bh    = ws + Nf;                     // Nf
  __bf16* m16  = (__bf16*)(ws + 2*Nf);        // Ee*64 bf16 = 32*Es floats
  int2*  pairs = (int2*)(ws + 2*Nf + 32*Es);  // Es int2 = 2*Es floats
  int*   cnt   = (int*)(pairs + Es);          // Nn
  int*   cnt2  = cnt + Nn;                    // Nn
  float* est   = (float*)(cnt2 + Nn);         // 128
  float* nst   = est + 128;                   // 128
  int*   rowp  = (int*)(nst + 128);           // Nn+1
  size_t woff  = 2*Nf + 32*Es + 2*Es + 2*(size_t)Nn + 256 + (size_t)Nn + 1;
  woff = (woff + 15) & ~(size_t)15;
  bf16x8* Wp   = (bf16x8*)(ws + woff);        // 2560 frags
  bf16x8* Wq   = Wp + 2560;                   // 1536 frags

  float* xo = (float*)d_out;
  float* yo = xo + Nf;

  // zero: cnt, cnt2, est, nst (contiguous, 2*Nn+256 ints)
  int nz4 = (int)((2*(size_t)Nn + 256) >> 2);
  zero_k<<<256,256,0,stream>>>((int4*)cnt, nz4);

  wcvt<<<16,256,0,stream>>>(W_sg,W_dg,W_eg,W_su,W_du,Wp,Wq);

  int ntn = Nn/16;
  node_xform<<<(ntn+3)/4,256,0,stream>>>(nf,Wp,b_su,b_du,A_src,Bh,ntn);
  hist_k<<<2048,256,0,stream>>>(dst,cnt,Ee);
  scan_k<<<1,1024,0,stream>>>(cnt,rowp,Nn);
  fill_k<<<2048,256,0,stream>>>(src,dst,rowp,cnt2,pairs,Ee);
  int nte = Ee/16;
  phaseA<<<4096,256,0,stream>>>(ef,nf,src,dst,b_sg,b_dg,b_eg,Wq,m16,nte);
  phaseB<<<4096,256,0,stream>>>(m16,pairs,Bh,rowp,A_src,est,nst,Nn);
  node_final<<<2048,256,0,stream>>>(nf,A_src,nst,gn,btn,xo,Nn);
  edge_final<<<4096,256,0,stream>>>(m16,ef,est,ge,bte,yo,
                                    1.f/(float)Ee,(long)Ee);
}

// Round 12
// 932.226 us; speedup vs baseline: 1.0466x; 1.0182x over previous
//
#include <hip/hip_runtime.h>
#include <hip/hip_bf16.h>

typedef __attribute__((ext_vector_type(8))) __bf16 bf16x8;
typedef __attribute__((ext_vector_type(4))) float f32x4;

#define MFMA(a,b,c) __builtin_amdgcn_mfma_f32_16x16x32_bf16((a),(b),(c),0,0,0)

__device__ __forceinline__ bf16x8 cvt8(float4 a, float4 b){
  bf16x8 r;
  r[0]=(__bf16)a.x; r[1]=(__bf16)a.y; r[2]=(__bf16)a.z; r[3]=(__bf16)a.w;
  r[4]=(__bf16)b.x; r[5]=(__bf16)b.y; r[6]=(__bf16)b.z; r[7]=(__bf16)b.w;
  return r;
}

// ---- fused setup: blocks 0-15 pack weights (Wp 2560 + Wq 1536 frags),
// blocks 16+ zero the counter/stat region.
__global__ void setup_k(const float* __restrict__ W_sg, const float* __restrict__ W_dg,
                        const float* __restrict__ W_eg, const float* __restrict__ W_su,
                        const float* __restrict__ W_du,
                        bf16x8* __restrict__ Wp, bf16x8* __restrict__ Wq,
                        int4* __restrict__ zp, int nz4){
  if (blockIdx.x < 16){
    int tid = blockIdx.x*256 + threadIdx.x;
    if (tid >= 2560 + 1536) return;
    int lane = tid & 63, g = lane>>4, c = lane&15;
    if (tid < 2560){
      int frag = (tid>>6)&7, m = tid>>9;
      const float* Ws[5] = {W_sg, W_dg, W_eg, W_su, W_du};
      const float* W = Ws[m];
      int kt = frag>>2, nt = frag&3;
      bf16x8 v;
      #pragma unroll
      for (int j=0;j<8;j++) v[j] = (__bf16)W[(kt*32+g*8+j)*64 + nt*16 + c];
      Wp[tid] = v;
    } else {
      int t2 = tid - 2560;
      int frag = (t2>>6)&7, m = t2>>9;   // 0..2
      const float* Ws[3] = {W_eg, W_sg, W_dg};
      const float* W = Ws[m];
      int mt = frag>>1, kh = frag&1;
      bf16x8 v;
      #pragma unroll
      for (int j=0;j<8;j++) v[j] = (__bf16)W[(kh*32+g*8+j)*64 + mt*16 + c];
      Wq[t2] = v;
    }
  } else {
    int i = (blockIdx.x-16)*256 + threadIdx.x, st = (gridDim.x-16)*256;
    for (; i<nz4; i+=st) zp[i] = make_int4(0,0,0,0);
  }
}

// ---- fused: blocks [0,nxf) node transforms; blocks [nxf,+) dst histogram.
__global__ __launch_bounds__(256) void xform_hist_k(
    const float* __restrict__ nf, const bf16x8* __restrict__ Wp,
    const float* __restrict__ b_su, const float* __restrict__ b_du,
    float* __restrict__ A_src, float* __restrict__ Bh, int ntiles, int nxf,
    const int* __restrict__ dst, int* __restrict__ cnt, int E)
{
  if ((int)blockIdx.x < nxf){
    int lane = threadIdx.x & 63;
    int gw = blockIdx.x*4 + (threadIdx.x>>6);
    if (gw >= ntiles) return;
    int g = lane>>4, c = lane&15;
    long base = (long)gw*16;
    const float* rp = nf + (base + c)*64 + g*8;
    float4 a0 = *(const float4*)rp,      a1 = *(const float4*)(rp+4);
    float4 a2 = *(const float4*)(rp+32), a3 = *(const float4*)(rp+36);
    bf16x8 A0 = cvt8(a0,a1), A1 = cvt8(a2,a3);
    const float* biases[2] = {b_su,b_du};
    float* outs[2] = {A_src,Bh};
    const int mats[2] = {3,4};
    #pragma unroll
    for (int i=0;i<2;i++){
      #pragma unroll
      for (int nt=0;nt<4;nt++){
        f32x4 acc = {0.f,0.f,0.f,0.f};
        acc = MFMA(A0, Wp[(mats[i]*8+nt)*64+lane],   acc);
        acc = MFMA(A1, Wp[(mats[i]*8+4+nt)*64+lane], acc);
        int col = c + nt*16;
        float bb = biases[i][col];
        #pragma unroll
        for (int e=0;e<4;e++) outs[i][(base+4*g+e)*64 + col] = acc[e] + bb;
      }
    }
  } else {
    int nb = gridDim.x - nxf;
    int i = (blockIdx.x-nxf)*256 + threadIdx.x, st = nb*256;
    for (; i<E; i+=st) atomicAdd(&cnt[dst[i]], 1);
  }
}

__global__ __launch_bounds__(1024) void scan_k(const int* __restrict__ cnt,
                                               int* __restrict__ row, int Nn){
  __shared__ int part[1024];
  int t = threadIdx.x;
  int C = (Nn + 1023) >> 10;
  int lo = t*C;
  int hi = lo + C; if (hi > Nn) hi = Nn;
  int s = 0;
  for (int i=lo; i<hi; i++) s += cnt[i];
  part[t] = s;
  __syncthreads();
  for (int off=1; off<1024; off<<=1){
    int v = part[t];
    int u = (t>=off) ? part[t-off] : 0;
    __syncthreads();
    part[t] = v + u;
    __syncthreads();
  }
  int excl = (t==0) ? 0 : part[t-1];
  for (int i=lo; i<hi; i++){ row[i] = excl; excl += cnt[i]; }
  if (t==1023) row[Nn] = excl;
}

// ---- fused: blocks [0,NFILL) CSR fill; blocks [NFILL,+) phaseA.
// fill only feeds phaseB (next launch); phaseA is independent of it.
#define NFILL 1024
__global__ __launch_bounds__(256) void fillA_k(
    const int* __restrict__ src, const int* __restrict__ dst,
    const int* __restrict__ rowp, int* __restrict__ cnt2,
    int2* __restrict__ pairs, int E,
    const float* __restrict__ ef, const float* __restrict__ nf,
    const float* __restrict__ b_sg, const float* __restrict__ b_dg,
    const float* __restrict__ b_eg,
    const bf16x8* __restrict__ Wq,
    __bf16* __restrict__ m16, int ntiles)
{
  __shared__ bf16x8 wl[24*64];
  if (blockIdx.x < NFILL){
    int i = blockIdx.x*256 + threadIdx.x, st = NFILL*256;
    for (; i<E; i+=st){
      int d = dst[i];
      int pos = rowp[d] + atomicAdd(&cnt2[d], 1);
      pairs[pos] = make_int2(i, src[i]);
    }
    return;
  }
  {
    int t = threadIdx.x;
    #pragma unroll
    for (int i=0;i<6;i++) wl[i*256+t] = Wq[i*256+t];
  }
  __syncthreads();
  int lane = threadIdx.x & 63, g = lane>>4, c = lane&15;
  int gw = (blockIdx.x-NFILL)*4 + (threadIdx.x>>6);
  int nw = (gridDim.x-NFILL)*4;
  float bias2[4][4];
  #pragma unroll
  for (int mt=0;mt<4;mt++)
    #pragma unroll
    for (int e=0;e<4;e++){
      int f = mt*16 + 4*g + e;
      bias2[mt][e] = b_sg[f] + b_dg[f] + b_eg[f];
    }
  int sc = 0, dc = 0;
  if (gw < ntiles){ sc = src[(long)gw*16 + c]; dc = dst[(long)gw*16 + c]; }
  for (int tt=gw; tt<ntiles; tt+=nw){
    long base = (long)tt*16;
    int tn = tt + nw;
    int sn = sc, dn = dc;
    if (tn < ntiles){ sn = src[(long)tn*16 + c]; dn = dst[(long)tn*16 + c]; }
    const float* rpe = ef + (base+c)*64 + g*8;
    const float* rps = nf + (long)sc*64 + g*8;
    const float* rpd = nf + (long)dc*64 + g*8;
    float4 e0=*(const float4*)rpe,      e1=*(const float4*)(rpe+4);
    float4 e2=*(const float4*)(rpe+32), e3=*(const float4*)(rpe+36);
    float4 s0=*(const float4*)rps,      s1=*(const float4*)(rps+4);
    float4 s2=*(const float4*)(rps+32), s3=*(const float4*)(rps+36);
    float4 d0=*(const float4*)rpd,      d1=*(const float4*)(rpd+4);
    float4 d2=*(const float4*)(rpd+32), d3=*(const float4*)(rpd+36);
    bf16x8 BE0=cvt8(e0,e1), BE1=cvt8(e2,e3);
    bf16x8 BS0=cvt8(s0,s1), BS1=cvt8(s2,s3);
    bf16x8 BD0=cvt8(d0,d1), BD1=cvt8(d2,d3);
    #pragma unroll
    for (int mt=0;mt<4;mt++){
      f32x4 am = {0.f,0.f,0.f,0.f};
      am = MFMA(wl[((0*4+mt)*2+0)*64+lane], BE0, am);
      am = MFMA(wl[((0*4+mt)*2+1)*64+lane], BE1, am);
      am = MFMA(wl[((1*4+mt)*2+0)*64+lane], BS0, am);
      am = MFMA(wl[((1*4+mt)*2+1)*64+lane], BS1, am);
      am = MFMA(wl[((2*4+mt)*2+0)*64+lane], BD0, am);
      am = MFMA(wl[((2*4+mt)*2+1)*64+lane], BD1, am);
      union { __bf16 h[4]; uint2 u; } pk;
      #pragma unroll
      for (int e=0;e<4;e++) pk.h[e] = (__bf16)(am[e] + bias2[mt][e]);
      *(uint2*)(m16 + (base+c)*64 + mt*16 + 4*g) = pk.u;
    }
    sc = sn; dc = dn;
  }
}

// ---- phaseB: node-major over CSR rows; 8-edge unroll.
__global__ __launch_bounds__(256) void phaseB(
    const __bf16* __restrict__ m16, const int2* __restrict__ pairs,
    const float* __restrict__ Bh, const int* __restrict__ rowp,
    float* __restrict__ A_src,
    float* __restrict__ est, float* __restrict__ nst, int Nn)
{
  __shared__ float sst[256];
  sst[threadIdx.x] = 0.f;
  __syncthreads();
  int lane = threadIdx.x & 63, w = threadIdx.x>>6;
  int chunk = (Nn + gridDim.x - 1)/gridDim.x;
  int n0 = blockIdx.x*chunk;
  int n1 = n0 + chunk; if (n1 > Nn) n1 = Nn;
  float e1=0.f, e2=0.f, p1=0.f, p2=0.f;
  for (int n=n0+w; n<n1; n+=4){
    int r0 = rowp[n], r1 = rowp[n+1];
    float ssum=0.f, bsum=0.f;
    int r = r0;
    for (; r+8 <= r1; r+=8){
      int2 q[8];
      #pragma unroll
      for (int j=0;j<8;j++) q[j] = pairs[r+j];
      float mv[8], bh[8];
      #pragma unroll
      for (int j=0;j<8;j++) mv[j] = (float)m16[(long)q[j].x*64 + lane];
      #pragma unroll
      for (int j=0;j<8;j++) bh[j] = Bh[(long)q[j].y*64 + lane];
      #pragma unroll
      for (int j=0;j<8;j++){
        float sg = 1.f/(1.f+__expf(-mv[j]));
        ssum += sg; bsum += bh[j]*sg;
        e1 += mv[j]; e2 += mv[j]*mv[j];
      }
    }
    for (; r < r1; ++r){
      int2 q0 = pairs[r];
      float mv0 = (float)m16[(long)q0.x*64 + lane];
      float bh0 = Bh[(long)q0.y*64 + lane];
      float sg0 = 1.f/(1.f+__expf(-mv0));
      ssum += sg0; bsum += bh0*sg0;
      e1 += mv0;   e2 += mv0*mv0;
    }
    long xi = (long)n*64 + lane;
    float xp = A_src[xi] + bsum/(ssum+1e-6f);
    A_src[xi] = xp;
    p1 += xp; p2 += xp*xp;
  }
  atomicAdd(&sst[lane],     e1);
  atomicAdd(&sst[64+lane],  e2);
  atomicAdd(&sst[128+lane], p1);
  atomicAdd(&sst[192+lane], p2);
  __syncthreads();
  int t = threadIdx.x;
  if (t < 128) atomicAdd(&est[t], sst[t]);
  else         atomicAdd(&nst[t-128], sst[t]);
}

// ---- fused finals: blocks [0,NNF) x-output; blocks [NNF,+) y-output.
#define NNF 1024
__global__ __launch_bounds__(256) void finals_k(
    const float* __restrict__ nf, const float* __restrict__ xpre,
    const float* __restrict__ nst, const float* __restrict__ gn,
    const float* __restrict__ btn, float* __restrict__ xo, int Nn,
    const __bf16* __restrict__ m16, const float* __restrict__ ef,
    const float* __restrict__ est, const float* __restrict__ ge,
    const float* __restrict__ bte, float* __restrict__ y, float invE, long E)
{
  if (blockIdx.x < NNF){
    long tid = (long)blockIdx.x*256 + threadIdx.x;
    long stride = (long)NNF*256;
    int col = (int)(tid & 63);
    float invN = 1.f/(float)Nn;
    float mu = nst[col]*invN;
    float var = nst[64+col]*invN - mu*mu;
    float rs = rsqrtf(var + 1e-5f);
    float aa = gn[col]*rs;
    float bb = btn[col] - mu*aa;
    long total = (long)Nn*64;
    for (long i=tid; i<total; i+=stride){
      float z = xpre[i]*aa + bb;
      xo[i] = nf[i] + z/(1.f+__expf(-z));
    }
  } else {
    int oct = threadIdx.x & 7;
    float aa[8], bb[8];
    #pragma unroll
    for (int j=0;j<8;j++){
      int col = oct*8 + j;
      float mu = est[col]*invE;
      float var = est[64+col]*invE - mu*mu;
      float rs = rsqrtf(var + 1e-5f);
      float ga = ge[col]*rs;
      aa[j] = ga; bb[j] = bte[col] - mu*ga;
    }
    long tid = (long)(blockIdx.x-NNF)*256 + threadIdx.x;
    long pstep = ((long)(gridDim.x-NNF)*256) >> 3;
    for (long p = tid>>3; p < E; p += pstep){
      bf16x8 mv = *(const bf16x8*)&m16[p*64 + oct*8];
      const float* rp = ef + p*64 + oct*8;
      float4 f0 = *(const float4*)rp, f1 = *(const float4*)(rp+4);
      float o[8];
      #pragma unroll
      for (int j=0;j<8;j++){
        float z = aa[j]*(float)mv[j] + bb[j];
        float ev = (j<4) ? ((const float*)&f0)[j] : ((const float*)&f1)[j-4];
        o[j] = ev + z/(1.f+__expf(-z));
      }
      float* yp = y + p*64 + oct*8;
      *(float4*)yp     = make_float4(o[0],o[1],o[2],o[3]);
      *(float4*)(yp+4) = make_float4(o[4],o[5],o[6],o[7]);
    }
  }
}

extern "C" void kernel_launch(void* const* d_in, const int* in_sizes, int n_in,
                              void* d_out, int out_size, void* d_ws, size_t ws_size,
                              hipStream_t stream){
  const float* nf  = (const float*)d_in[0];
  const float* ef  = (const float*)d_in[1];
  const int*   src = (const int*)d_in[2];
  const int*   dst = (const int*)d_in[3];
  const float* W_sg=(const float*)d_in[4];  const float* b_sg=(const float*)d_in[5];
  const float* W_dg=(const float*)d_in[6];  const float* b_dg=(const float*)d_in[7];
  const float* W_eg=(const float*)d_in[8];  const float* b_eg=(const float*)d_in[9];
  const float* W_su=(const float*)d_in[10]; const float* b_su=(const float*)d_in[11];
  const float* W_du=(const float*)d_in[12]; const float* b_du=(const float*)d_in[13];
  const float* gn=(const float*)d_in[14];   const float* btn=(const float*)d_in[15];
  const float* ge=(const float*)d_in[16];   const float* bte=(const float*)d_in[17];

  int Nn = in_sizes[0]/64;
  int Ee = in_sizes[2];
  size_t Nf = (size_t)Nn*64;
  size_t Es = (size_t)Ee;

  float* ws    = (float*)d_ws;
  float* A_src = ws;                          // Nf (becomes x_pre)
  float* Bh    = ws + Nf;                     // Nf
  __bf16* m16  = (__bf16*)(ws + 2*Nf);        // 32*Es floats
  int2*  pairs = (int2*)(ws + 2*Nf + 32*Es);  // 2*Es floats
  int*   cnt   = (int*)(pairs + Es);          // Nn
  int*   cnt2  = cnt + Nn;                    // Nn
  float* est   = (float*)(cnt2 + Nn);         // 128
  float* nst   = est + 128;                   // 128
  int*   rowp  = (int*)(nst + 128);           // Nn+1
  size_t woff  = 2*Nf + 32*Es + 2*Es + 2*(size_t)Nn + 256 + (size_t)Nn + 1;
  woff = (woff + 15) & ~(size_t)15;
  bf16x8* Wp   = (bf16x8*)(ws + woff);        // 2560 frags
  bf16x8* Wq   = Wp + 2560;                   // 1536 frags

  float* xo = (float*)d_out;
  float* yo = xo + Nf;

  int nz4 = (int)((2*(size_t)Nn + 256) >> 2);
  setup_k<<<272,256,0,stream>>>(W_sg,W_dg,W_eg,W_su,W_du,Wp,Wq,(int4*)cnt,nz4);

  int ntn = Nn/16;
  int nxf = (ntn+3)/4;
  xform_hist_k<<<nxf+2048,256,0,stream>>>(nf,Wp,b_su,b_du,A_src,Bh,ntn,nxf,
                                          dst,cnt,Ee);
  scan_k<<<1,1024,0,stream>>>(cnt,rowp,Nn);
  int nte = Ee/16;
  fillA_k<<<NFILL+4096,256,0,stream>>>(src,dst,rowp,cnt2,pairs,Ee,
                                       ef,nf,b_sg,b_dg,b_eg,Wq,m16,nte);
  phaseB<<<4096,256,0,stream>>>(m16,pairs,Bh,rowp,A_src,est,nst,Nn);
  finals_k<<<NNF+4096,256,0,stream>>>(nf,A_src,nst,gn,btn,xo,Nn,
                                      m16,ef,est,ge,bte,yo,
                                      1.f/(float)Ee,(long)Ee);
}